// Round 1
// baseline (319.933 us; speedup 1.0000x reference)
//
#include <hip/hip_runtime.h>

#define NN 2048      // nodes per batch
#define FF 128       // features per node
#define KK 16        // top-K

// One block = 4 output rows of one batch. Inactive rows stream zeros
// (pure BW path); active rows (i < taus[b]) compute exact K-NN with
// lexicographic (d2, index) ordering matching jax.lax.top_k tie-breaking,
// then stream the 0/1 row. d2 computed with non-contracted fp32 ops to
// match the numpy reference bit-exactly.
__global__ __launch_bounds__(256) void knn_adj_kernel(
    const float* __restrict__ nodes,
    const int*   __restrict__ T_arr,
    const int*   __restrict__ tau_arr,
    float*       __restrict__ adj)
{
    const int b   = blockIdx.x;
    const int i0  = blockIdx.y << 2;          // first of 4 rows
    const int tid = threadIdx.x;
    const int wave = tid >> 6;
    const int lane = tid & 63;

    const int T   = T_arr[b];
    const int tau = tau_arr[b];

    float* block_out = adj + ((size_t)b * NN + i0) * NN;

    if (i0 >= tau) {
        // All 4 rows inactive: write 4*2048 zeros = 2048 float4, coalesced.
        float4 z = make_float4(0.f, 0.f, 0.f, 0.f);
        float4* out4 = (float4*)block_out;
        #pragma unroll
        for (int t = 0; t < 8; ++t)
            out4[tid + (t << 8)] = z;
        return;
    }

    const int M = T + tau;                    // src_valid: j < M (<= 2046 < NN)

    // Stage pos[b][0..M) into LDS (SoA: conflict-free, 2-way alias is free).
    __shared__ float sx[NN], sy[NN], sz[NN];
    for (int j = tid; j < M; j += 256) {
        const float* p = nodes + ((size_t)b * NN + j) * FF;
        sx[j] = p[0];
        sy[j] = p[1];
        sz[j] = p[2];
    }
    __syncthreads();

    const int i = i0 + wave;                  // this wave's sink row
    float* row_out = block_out + (size_t)wave * NN;

    if (i >= tau) {
        // Inactive row within an active block: stream zeros.
        float4 z = make_float4(0.f, 0.f, 0.f, 0.f);
        float4* out4 = (float4*)row_out;
        #pragma unroll
        for (int t = 0; t < 8; ++t)
            out4[lane + (t << 6)] = z;
        return;
    }

    // Sink position: global index g = T + i  (always < M <= N, no clip needed).
    const int g = T + i;
    const float sxv = sx[g], syv = sy[g], szv = sz[g];

    // Per-lane candidate keys, strided j = lane + 64*s.  Key = (d2_bits<<32)|(j+1):
    // uint order == (d2, j) lexicographic order (d2 >= 0 finite).  j+1 so the
    // minimal possible key is > 0 and "prev" threshold can start at 0.
    unsigned long long keys[32];
    #pragma unroll
    for (int s = 0; s < 32; ++s) {
        const int j = lane + (s << 6);
        unsigned long long key = ~0ull;
        if (j < M) {
            float dx = __fsub_rn(sxv, sx[j]);
            float dy = __fsub_rn(syv, sy[j]);
            float dz = __fsub_rn(szv, sz[j]);
            // strict IEEE, no FMA contraction: ((dx*dx + dy*dy) + dz*dz)
            float d2 = __fadd_rn(__fadd_rn(__fmul_rn(dx, dx), __fmul_rn(dy, dy)),
                                 __fmul_rn(dz, dz));
            key = ((unsigned long long)__float_as_uint(d2) << 32)
                | (unsigned int)(j + 1);
        }
        keys[s] = key;
    }

    const unsigned long long INF_HI = (unsigned long long)__float_as_uint(1e30f);

    // Select K smallest keys by repeated thresholded min + wave-wide min-reduce.
    // Record causal (j < i) hits in a per-lane column bitmask:
    //   column c is owned by lane (c>>2)&63, bit ((c>>8)<<2)|(c&3).
    unsigned int colmask = 0;
    unsigned long long prev = 0;
    for (int k = 0; k < KK; ++k) {
        unsigned long long m = ~0ull;
        #pragma unroll
        for (int s = 0; s < 32; ++s) {
            unsigned long long key = keys[s];
            if (key > prev && key < m) m = key;
        }
        #pragma unroll
        for (int off = 32; off > 0; off >>= 1) {
            unsigned long long o = __shfl_xor(m, off, 64);
            if (o < m) m = o;
        }
        if ((m >> 32) >= INF_HI) break;       // no more valid candidates
        prev = m;
        const int j = (int)(m & 0xffffffffu) - 1;
        if (j < i && ((j >> 2) & 63) == lane)
            colmask |= 1u << (((j >> 8) << 2) | (j & 3));
    }

    // Stream the row: iteration t covers columns t*256 + lane*4 .. +3 (coalesced).
    float4* out4 = (float4*)row_out;
    #pragma unroll
    for (int t = 0; t < 8; ++t) {
        float4 v;
        v.x = ((colmask >> (t * 4 + 0)) & 1u) ? 1.0f : 0.0f;
        v.y = ((colmask >> (t * 4 + 1)) & 1u) ? 1.0f : 0.0f;
        v.z = ((colmask >> (t * 4 + 2)) & 1u) ? 1.0f : 0.0f;
        v.w = ((colmask >> (t * 4 + 3)) & 1u) ? 1.0f : 0.0f;
        out4[(t << 6) + lane] = v;
    }
}

extern "C" void kernel_launch(void* const* d_in, const int* in_sizes, int n_in,
                              void* d_out, int out_size, void* d_ws, size_t ws_size,
                              hipStream_t stream) {
    const float* nodes = (const float*)d_in[0];
    const int*   T     = (const int*)d_in[1];
    const int*   taus  = (const int*)d_in[2];
    float*       adj   = (float*)d_out;

    const int B = in_sizes[1];               // T has B elements (16)
    dim3 grid(B, NN / 4);                    // 16 x 512 blocks, 256 thr each
    knn_adj_kernel<<<grid, dim3(256), 0, stream>>>(nodes, T, taus, adj);
}

// Round 2
// 316.119 us; speedup vs baseline: 1.0121x; 1.0121x over previous
//
#include <hip/hip_runtime.h>

#define NN 2048      // nodes per batch
#define FF 128       // features per node
#define KK 16        // top-K
#define INF_KEY 0xFFFFFFFFFFFFFFFFull

// ---------- exact (d2, index) key, bit-identical to the numpy reference ----
__device__ __forceinline__ unsigned long long make_key(const float4& s,
                                                       const float4& p, int j) {
    float dx = __fsub_rn(s.x, p.x);
    float dy = __fsub_rn(s.y, p.y);
    float dz = __fsub_rn(s.z, p.z);
    // strict IEEE, no FMA contraction: ((dx*dx + dy*dy) + dz*dz)
    float d2 = __fadd_rn(__fadd_rn(__fmul_rn(dx, dx), __fmul_rn(dy, dy)),
                         __fmul_rn(dz, dz));
    return ((unsigned long long)__float_as_uint(d2) << 32) | (unsigned)(j + 1);
}

// ---------- wave64 min-reduce via DPP (VALU pipe, no LDS/permute) ----------
__device__ __forceinline__ unsigned wave_min_u32(unsigned x) {
    int v = (int)x, t;
    t = __builtin_amdgcn_update_dpp(v, v, 0x111, 0xf, 0xf, false); // row_shr:1
    v = ((unsigned)t < (unsigned)v) ? t : v;
    t = __builtin_amdgcn_update_dpp(v, v, 0x112, 0xf, 0xf, false); // row_shr:2
    v = ((unsigned)t < (unsigned)v) ? t : v;
    t = __builtin_amdgcn_update_dpp(v, v, 0x114, 0xf, 0xf, false); // row_shr:4
    v = ((unsigned)t < (unsigned)v) ? t : v;
    t = __builtin_amdgcn_update_dpp(v, v, 0x118, 0xf, 0xf, false); // row_shr:8
    v = ((unsigned)t < (unsigned)v) ? t : v;
    t = __builtin_amdgcn_update_dpp(v, v, 0x142, 0xf, 0xf, false); // row_bcast:15
    v = ((unsigned)t < (unsigned)v) ? t : v;
    t = __builtin_amdgcn_update_dpp(v, v, 0x143, 0xf, 0xf, false); // row_bcast:31
    v = ((unsigned)t < (unsigned)v) ? t : v;
    return (unsigned)__builtin_amdgcn_readlane(v, 63);
}

// ============ kernel A: per-row KNN -> 2048-bit bitmap in d_ws =============
// block = 256 thr = 4 waves = 4 sink rows. Per lane: sorted top-4 queue of
// packed (d2,j+1) keys built in one LDS pass; 16 extraction rounds using a
// 32-bit DPP min on the head d2 + ballot index resolution; exact on-empty
// refill from LDS (rare) guarantees correctness when a lane holds >4 of the
// global top-16.
__global__ __launch_bounds__(256) void knn_bitmap_kernel(
    const float* __restrict__ nodes,
    const int*   __restrict__ T_arr,
    const int*   __restrict__ tau_arr,
    unsigned*    __restrict__ bm)
{
    const int b    = blockIdx.x;
    const int i0   = blockIdx.y << 2;
    const int tid  = threadIdx.x;
    const int wave = tid >> 6;
    const int lane = tid & 63;

    const int tau = tau_arr[b];
    if (i0 >= tau) return;                    // whole block inactive
    const int T = T_arr[b];
    const int M = T + tau;                    // src_valid: j < M (<= 2046)

    __shared__ float4 spos[NN];               // 32 KiB
    for (int j = tid; j < M; j += 256)
        spos[j] = *(const float4*)(nodes + ((size_t)b * NN + j) * FF);
    __syncthreads();

    const int i = i0 + wave;
    if (i >= tau) return;                     // inactive row in active block

    const float4 sp = spos[T + i];            // sink pos (T+i < M always)

    // ---- one-pass build of per-lane sorted top-4 queue ----
    unsigned long long q0 = INF_KEY, q1 = INF_KEY, q2 = INF_KEY, q3 = INF_KEY;
    const int S = (M + 63) >> 6;
    #pragma unroll 4
    for (int s = 0; s < S; ++s) {
        const int j = lane + (s << 6);
        if (j < M) {
            unsigned long long key = make_key(sp, spos[j], j);
            if (key < q3) {
                q3 = key;
                unsigned long long t;
                if (q3 < q2) { t = q2; q2 = q3; q3 = t; }
                if (q2 < q1) { t = q1; q1 = q2; q2 = t; }
                if (q1 < q0) { t = q0; q0 = q1; q1 = t; }
            }
        }
    }

    // ---- 16 extraction rounds ----
    unsigned colmask = 0;                       // this lane's 32-col word
    unsigned long long lastpop = 0;             // last key popped by THIS lane
    for (int k = 0; k < KK; ++k) {
        const unsigned hd = (unsigned)(q0 >> 32);
        const unsigned m  = wave_min_u32(hd);
        if (m == 0xFFFFFFFFu) break;            // all lanes exhausted

        const unsigned long long mask = __ballot(hd == m);
        unsigned jwin;
        if (__popcll(mask) == 1) {              // uniform branch, common case
            const int w = __builtin_ctzll(mask);
            jwin = (unsigned)__builtin_amdgcn_readlane((int)(unsigned)q0, w);
        } else {                                // d2 tie across lanes (rare)
            unsigned jc = (hd == m) ? (unsigned)q0 : 0xFFFFFFFFu;
            jwin = wave_min_u32(jc);
        }
        const int j = (int)jwin - 1;

        if (j < i && (j >> 5) == lane)          // causal + word ownership
            colmask |= 1u << (j & 31);

        // pop on the (unique) winner lane; refill from LDS if head empties
        if (hd == m && (unsigned)q0 == jwin) {
            lastpop = ((unsigned long long)m << 32) | jwin;
            q0 = q1; q1 = q2; q2 = q3; q3 = INF_KEY;
            if (q0 == INF_KEY) {                // rare: >4 hits in this lane
                unsigned long long best = INF_KEY;
                for (int s2 = 0; s2 < S; ++s2) {
                    const int jj = lane + (s2 << 6);
                    if (jj < M) {
                        unsigned long long kk = make_key(sp, spos[jj], jj);
                        if (kk > lastpop && kk < best) best = kk;
                    }
                }
                q0 = best;
            }
        }
    }

    bm[((size_t)b * NN + i) * 64 + lane] = colmask;   // coalesced 256 B/row
}

// ============ kernel B: pure-BW expansion of bitmaps -> 256 MB adj =========
__global__ __launch_bounds__(256) void write_adj_kernel(
    const unsigned* __restrict__ bm,
    const int*      __restrict__ tau_arr,
    float*          __restrict__ adj)
{
    const int b    = blockIdx.x;
    const int i0   = blockIdx.y << 2;
    const int tid  = threadIdx.x;
    const int wave = tid >> 6;
    const int lane = tid & 63;
    const int i    = i0 + wave;
    const int tau  = tau_arr[b];

    float4* out4 = (float4*)(adj + ((size_t)b * NN + i) * NN);

    if (i >= tau) {
        const float4 z = make_float4(0.f, 0.f, 0.f, 0.f);
        #pragma unroll
        for (int k = 0; k < 8; ++k)
            out4[(k << 6) + lane] = z;
        return;
    }

    const unsigned* row = bm + ((size_t)b * NN + i) * 64;
    #pragma unroll
    for (int k = 0; k < 8; ++k) {
        // cols c = 256k + 4*lane .. +3 ; word = c>>5 ; bits at 4*(lane&7)
        const unsigned w   = row[(k << 3) + (lane >> 3)];
        const unsigned nib = (w >> ((lane & 7) << 2)) & 0xFu;
        float4 v;
        v.x = (nib & 1u) ? 1.0f : 0.0f;
        v.y = (nib & 2u) ? 1.0f : 0.0f;
        v.z = (nib & 4u) ? 1.0f : 0.0f;
        v.w = (nib & 8u) ? 1.0f : 0.0f;
        out4[(k << 6) + lane] = v;
    }
}

// ============ fallback: round-1 fused kernel (used only if ws too small) ===
__global__ __launch_bounds__(256) void knn_adj_fused(
    const float* __restrict__ nodes,
    const int*   __restrict__ T_arr,
    const int*   __restrict__ tau_arr,
    float*       __restrict__ adj)
{
    const int b   = blockIdx.x;
    const int i0  = blockIdx.y << 2;
    const int tid = threadIdx.x;
    const int wave = tid >> 6;
    const int lane = tid & 63;
    const int T   = T_arr[b];
    const int tau = tau_arr[b];
    float* block_out = adj + ((size_t)b * NN + i0) * NN;

    if (i0 >= tau) {
        float4 z = make_float4(0.f, 0.f, 0.f, 0.f);
        float4* out4 = (float4*)block_out;
        #pragma unroll
        for (int t = 0; t < 8; ++t) out4[tid + (t << 8)] = z;
        return;
    }
    const int M = T + tau;
    __shared__ float sx[NN], sy[NN], sz[NN];
    for (int j = tid; j < M; j += 256) {
        const float* p = nodes + ((size_t)b * NN + j) * FF;
        sx[j] = p[0]; sy[j] = p[1]; sz[j] = p[2];
    }
    __syncthreads();
    const int i = i0 + wave;
    float* row_out = block_out + (size_t)wave * NN;
    if (i >= tau) {
        float4 z = make_float4(0.f, 0.f, 0.f, 0.f);
        float4* out4 = (float4*)row_out;
        #pragma unroll
        for (int t = 0; t < 8; ++t) out4[lane + (t << 6)] = z;
        return;
    }
    const int g = T + i;
    const float sxv = sx[g], syv = sy[g], szv = sz[g];
    unsigned long long keys[32];
    #pragma unroll
    for (int s = 0; s < 32; ++s) {
        const int j = lane + (s << 6);
        unsigned long long key = ~0ull;
        if (j < M) {
            float dx = __fsub_rn(sxv, sx[j]);
            float dy = __fsub_rn(syv, sy[j]);
            float dz = __fsub_rn(szv, sz[j]);
            float d2 = __fadd_rn(__fadd_rn(__fmul_rn(dx, dx), __fmul_rn(dy, dy)),
                                 __fmul_rn(dz, dz));
            key = ((unsigned long long)__float_as_uint(d2) << 32) | (unsigned)(j + 1);
        }
        keys[s] = key;
    }
    const unsigned long long INF_HI = (unsigned long long)__float_as_uint(1e30f);
    unsigned colmask = 0;
    unsigned long long prev = 0;
    for (int k = 0; k < KK; ++k) {
        unsigned long long m = ~0ull;
        #pragma unroll
        for (int s = 0; s < 32; ++s) {
            unsigned long long key = keys[s];
            if (key > prev && key < m) m = key;
        }
        #pragma unroll
        for (int off = 32; off > 0; off >>= 1) {
            unsigned long long o = __shfl_xor(m, off, 64);
            if (o < m) m = o;
        }
        if ((m >> 32) >= INF_HI) break;
        prev = m;
        const int j = (int)(m & 0xffffffffu) - 1;
        if (j < i && ((j >> 2) & 63) == lane)
            colmask |= 1u << (((j >> 8) << 2) | (j & 3));
    }
    float4* out4 = (float4*)row_out;
    #pragma unroll
    for (int t = 0; t < 8; ++t) {
        float4 v;
        v.x = ((colmask >> (t * 4 + 0)) & 1u) ? 1.0f : 0.0f;
        v.y = ((colmask >> (t * 4 + 1)) & 1u) ? 1.0f : 0.0f;
        v.z = ((colmask >> (t * 4 + 2)) & 1u) ? 1.0f : 0.0f;
        v.w = ((colmask >> (t * 4 + 3)) & 1u) ? 1.0f : 0.0f;
        out4[(t << 6) + lane] = v;
    }
}

extern "C" void kernel_launch(void* const* d_in, const int* in_sizes, int n_in,
                              void* d_out, int out_size, void* d_ws, size_t ws_size,
                              hipStream_t stream) {
    const float* nodes = (const float*)d_in[0];
    const int*   T     = (const int*)d_in[1];
    const int*   taus  = (const int*)d_in[2];
    float*       adj   = (float*)d_out;
    const int B = in_sizes[1];

    const size_t bm_bytes = (size_t)B * NN * 64 * sizeof(unsigned);
    if (ws_size >= bm_bytes) {
        unsigned* bm = (unsigned*)d_ws;
        dim3 grid(B, NN / 4);
        knn_bitmap_kernel<<<grid, dim3(256), 0, stream>>>(nodes, T, taus, bm);
        write_adj_kernel<<<grid, dim3(256), 0, stream>>>(bm, taus, adj);
    } else {
        dim3 grid(B, NN / 4);
        knn_adj_fused<<<grid, dim3(256), 0, stream>>>(nodes, T, taus, adj);
    }
}

// Round 3
// 276.314 us; speedup vs baseline: 1.1579x; 1.1441x over previous
//
#include <hip/hip_runtime.h>

#define NN 2048      // nodes per batch
#define FF 128       // features per node
#define KK 16        // top-K
#define INF_KEY 0xFFFFFFFFFFFFFFFFull

// ---------- wave64 min-reduce via DPP (VALU pipe, no LDS/permute) ----------
__device__ __forceinline__ unsigned wave_min_u32(unsigned x) {
    int v = (int)x, t;
    t = __builtin_amdgcn_update_dpp(v, v, 0x111, 0xf, 0xf, false); // row_shr:1
    v = ((unsigned)t < (unsigned)v) ? t : v;
    t = __builtin_amdgcn_update_dpp(v, v, 0x112, 0xf, 0xf, false); // row_shr:2
    v = ((unsigned)t < (unsigned)v) ? t : v;
    t = __builtin_amdgcn_update_dpp(v, v, 0x114, 0xf, 0xf, false); // row_shr:4
    v = ((unsigned)t < (unsigned)v) ? t : v;
    t = __builtin_amdgcn_update_dpp(v, v, 0x118, 0xf, 0xf, false); // row_shr:8
    v = ((unsigned)t < (unsigned)v) ? t : v;
    t = __builtin_amdgcn_update_dpp(v, v, 0x142, 0xf, 0xf, false); // row_bcast:15
    v = ((unsigned)t < (unsigned)v) ? t : v;
    t = __builtin_amdgcn_update_dpp(v, v, 0x143, 0xf, 0xf, false); // row_bcast:31
    v = ((unsigned)t < (unsigned)v) ? t : v;
    return (unsigned)__builtin_amdgcn_readlane(v, 63);
}

// Fused: one block = 4 rows of one batch. Inactive rows stream zeros (pure
// BW); active rows build a per-lane sorted top-4 queue of packed (d2,j+1)
// keys in one LDS pass (SoA sx/sy/sz: 2-way bank alias, free), extract the
// global top-16 with 32-bit DPP mins (exact refill covers >4-per-lane), and
// stream the 0/1 row via a 1 KB LDS word table (coalesced float4 stores).
// d2 uses strict-IEEE non-contracted ops; key order == numpy/jax top_k
// (d2, index) lexicographic order -> absmax 0 (verified R1/R2).
__global__ __launch_bounds__(256) void knn_adj_fused(
    const float* __restrict__ nodes,
    const int*   __restrict__ T_arr,
    const int*   __restrict__ tau_arr,
    float*       __restrict__ adj)
{
    const int b    = blockIdx.x;
    const int i0   = blockIdx.y << 2;
    const int tid  = threadIdx.x;
    const int wave = tid >> 6;
    const int lane = tid & 63;

    const int tau = tau_arr[b];
    float* block_out = adj + ((size_t)b * NN + i0) * NN;

    if (i0 >= tau) {                          // whole block inactive: 32 KB zeros
        const float4 z = make_float4(0.f, 0.f, 0.f, 0.f);
        float4* out4 = (float4*)block_out;
        #pragma unroll
        for (int t = 0; t < 8; ++t)
            out4[tid + (t << 8)] = z;
        return;
    }

    const int T = T_arr[b];
    const int M = T + tau;                    // src_valid: j < M (<= 2046)

    __shared__ float sx[NN], sy[NN], sz[NN];  // 24 KiB, SoA: conflict-free
    __shared__ unsigned swords[4][64];        // 1 KiB: per-wave column words
    for (int j = tid; j < M; j += 256) {
        const float* p = nodes + ((size_t)b * NN + j) * FF;
        sx[j] = p[0];
        sy[j] = p[1];
        sz[j] = p[2];
    }
    __syncthreads();

    const int i = i0 + wave;
    float4* out4 = (float4*)(block_out + (size_t)wave * NN);

    if (i >= tau) {                           // inactive row in active block
        const float4 z = make_float4(0.f, 0.f, 0.f, 0.f);
        #pragma unroll
        for (int t = 0; t < 8; ++t)
            out4[(t << 6) + lane] = z;
        return;
    }

    const int g = T + i;                      // sink global index (< M always)
    const float sxv = sx[g], syv = sy[g], szv = sz[g];

    // ---- one-pass build of per-lane sorted top-4 queue ----
    unsigned long long q0 = INF_KEY, q1 = INF_KEY, q2 = INF_KEY, q3 = INF_KEY;
    const int S = (M + 63) >> 6;
    #pragma unroll 4
    for (int s = 0; s < S; ++s) {
        const int j = lane + (s << 6);
        if (j < M) {
            float dx = __fsub_rn(sxv, sx[j]);
            float dy = __fsub_rn(syv, sy[j]);
            float dz = __fsub_rn(szv, sz[j]);
            float d2 = __fadd_rn(__fadd_rn(__fmul_rn(dx, dx), __fmul_rn(dy, dy)),
                                 __fmul_rn(dz, dz));
            unsigned long long key =
                ((unsigned long long)__float_as_uint(d2) << 32) | (unsigned)(j + 1);
            if (key < q3) {
                q3 = key;
                unsigned long long t;
                if (q3 < q2) { t = q2; q2 = q3; q3 = t; }
                if (q2 < q1) { t = q1; q1 = q2; q2 = t; }
                if (q1 < q0) { t = q0; q0 = q1; q1 = t; }
            }
        }
    }

    // ---- 16 extraction rounds: DPP min on head d2 + ballot index resolve ----
    unsigned colmask = 0;                     // this lane's cols [32*lane, +32)
    unsigned long long lastpop = 0;
    for (int k = 0; k < KK; ++k) {
        const unsigned hd = (unsigned)(q0 >> 32);
        const unsigned m  = wave_min_u32(hd);
        if (m == 0xFFFFFFFFu) break;          // all lanes exhausted

        const unsigned long long mask = __ballot(hd == m);
        unsigned jwin;
        if (__popcll(mask) == 1) {            // unique head d2 (common case)
            const int w = __builtin_ctzll(mask);
            jwin = (unsigned)__builtin_amdgcn_readlane((int)(unsigned)q0, w);
        } else {                              // cross-lane d2 tie (rare)
            unsigned jc = (hd == m) ? (unsigned)q0 : 0xFFFFFFFFu;
            jwin = wave_min_u32(jc);
        }
        const int j = (int)jwin - 1;

        if (j < i && (j >> 5) == lane)        // causal + word ownership
            colmask |= 1u << (j & 31);

        if (hd == m && (unsigned)q0 == jwin) {  // pop on the winner lane
            lastpop = ((unsigned long long)m << 32) | jwin;
            q0 = q1; q1 = q2; q2 = q3; q3 = INF_KEY;
            if (q0 == INF_KEY) {              // rare: >4 global hits this lane
                unsigned long long best = INF_KEY;
                for (int s2 = 0; s2 < S; ++s2) {
                    const int jj = lane + (s2 << 6);
                    if (jj < M) {
                        float dx = __fsub_rn(sxv, sx[jj]);
                        float dy = __fsub_rn(syv, sy[jj]);
                        float dz = __fsub_rn(szv, sz[jj]);
                        float d2 = __fadd_rn(
                            __fadd_rn(__fmul_rn(dx, dx), __fmul_rn(dy, dy)),
                            __fmul_rn(dz, dz));
                        unsigned long long kk =
                            ((unsigned long long)__float_as_uint(d2) << 32)
                            | (unsigned)(jj + 1);
                        if (kk > lastpop && kk < best) best = kk;
                    }
                }
                q0 = best;
            }
        }
    }

    // ---- route words through LDS (same wave: no barrier), stream the row ----
    swords[wave][lane] = colmask;
    #pragma unroll
    for (int k = 0; k < 8; ++k) {
        // cols c = 256k + 4*lane .. +3 ; word = 8k + (lane>>3) (broadcast read)
        const unsigned w   = swords[wave][(k << 3) + (lane >> 3)];
        const unsigned nib = (w >> ((lane & 7) << 2)) & 0xFu;
        float4 v;
        v.x = (nib & 1u) ? 1.0f : 0.0f;
        v.y = (nib & 2u) ? 1.0f : 0.0f;
        v.z = (nib & 4u) ? 1.0f : 0.0f;
        v.w = (nib & 8u) ? 1.0f : 0.0f;
        out4[(k << 6) + lane] = v;
    }
}

extern "C" void kernel_launch(void* const* d_in, const int* in_sizes, int n_in,
                              void* d_out, int out_size, void* d_ws, size_t ws_size,
                              hipStream_t stream) {
    const float* nodes = (const float*)d_in[0];
    const int*   T     = (const int*)d_in[1];
    const int*   taus  = (const int*)d_in[2];
    float*       adj   = (float*)d_out;
    const int B = in_sizes[1];               // T has B elements (16)

    dim3 grid(B, NN / 4);                    // 16 x 512 blocks, 256 thr each
    knn_adj_fused<<<grid, dim3(256), 0, stream>>>(nodes, T, taus, adj);
}